// Round 5
// baseline (344.283 us; speedup 1.0000x reference)
//
#include <hip/hip_runtime.h>
#include <hip/hip_bf16.h>

typedef __attribute__((ext_vector_type(8))) short bf16x8;
typedef __attribute__((ext_vector_type(4))) short bf16x4;
typedef __attribute__((ext_vector_type(4))) float f32x4;

__device__ __forceinline__ short f2bf(float f){
  __hip_bfloat16 h = __float2bfloat16(f);
  return __builtin_bit_cast(short, h);
}
__device__ __forceinline__ float bf2f(short s){
  unsigned u = ((unsigned)(unsigned short)s) << 16;
  return __builtin_bit_cast(float, u);
}

__device__ __forceinline__ void gload_lds16(const short* g, char* l){
  __builtin_amdgcn_global_load_lds(
      (const __attribute__((address_space(1))) void*)g,
      (__attribute__((address_space(3))) void*)l, 16, 0, 0);
}

#define SB0() __builtin_amdgcn_sched_barrier(0)
#define LGKM0() do{ asm volatile("s_waitcnt lgkmcnt(0)" ::: "memory"); SB0(); }while(0)
#define LGKM4() do{ asm volatile("s_waitcnt lgkmcnt(4)" ::: "memory"); SB0(); }while(0)

// ---------------- GroupNorm stats: one block per (batch, group) ----------------
__global__ __launch_bounds__(256) void gn_stats(const float* __restrict__ x,
                                                float* __restrict__ stats){
  int b = blockIdx.x >> 5, g = blockIdx.x & 31;
  const float4* p = (const float4*)(x + ((long long)b*512 + g*16)*4096);
  float s = 0.f, s2 = 0.f;
  for (int i = threadIdx.x; i < 16384; i += 256){
    float4 v = p[i];
    s  += v.x + v.y + v.z + v.w;
    s2 += v.x*v.x + v.y*v.y + v.z*v.z + v.w*v.w;
  }
  #pragma unroll
  for (int o = 32; o; o >>= 1){ s += __shfl_xor(s, o); s2 += __shfl_xor(s2, o); }
  __shared__ float rs[4], rs2[4];
  int wid = threadIdx.x >> 6;
  if ((threadIdx.x & 63) == 0){ rs[wid] = s; rs2[wid] = s2; }
  __syncthreads();
  if (threadIdx.x == 0){
    float S  = rs[0]+rs[1]+rs[2]+rs[3];
    float S2 = rs2[0]+rs2[1]+rs2[2]+rs2[3];
    float mean = S * (1.f/65536.f);
    float var  = S2 * (1.f/65536.f) - mean*mean;
    stats[blockIdx.x*2]   = mean;
    stats[blockIdx.x*2+1] = rsqrtf(var + 1e-6f);
  }
}

// ------------- GN apply + transpose [B,C,N] -> h bf16 [B,N,C] ------------------
__global__ __launch_bounds__(256) void gn_apply(const float* __restrict__ x,
                                                const float* __restrict__ stats,
                                                const float* __restrict__ gw,
                                                const float* __restrict__ gb,
                                                short* __restrict__ h){
  __shared__ float tile[128][65];
  int b  = blockIdx.y;
  int n0 = blockIdx.x * 64;
  int t  = threadIdx.x;
  const float* xb = x + (long long)b*512*4096;
  for (int cc = 0; cc < 4; cc++){
    int c0 = cc*128;
    #pragma unroll
    for (int r = 0; r < 128; r += 4){
      int c = r + (t >> 6);
      tile[c][t & 63] = xb[(long long)(c0+c)*4096 + n0 + (t & 63)];
    }
    __syncthreads();
    int n = t >> 2, cp = (t & 3)*32;
    short tmp[32];
    #pragma unroll
    for (int j = 0; j < 32; j++){
      int c = c0 + cp + j;
      float mean = stats[(b*32 + (c >> 4))*2];
      float rstd = stats[(b*32 + (c >> 4))*2 + 1];
      float v = (tile[cp+j][n] - mean)*rstd*gw[c] + gb[c];
      tmp[j] = f2bf(v);
    }
    long long ho = ((long long)b*4096 + n0 + n)*512 + c0 + cp;
    #pragma unroll
    for (int j2 = 0; j2 < 4; j2++){
      bf16x8 v8;
      #pragma unroll
      for (int e = 0; e < 8; e++) v8[e] = tmp[j2*8 + e];
      *(bf16x8*)&h[ho + j2*8] = v8;
    }
    __syncthreads();
  }
}

// ---------- fp32 -> bf16 conversion for all 4 weight matrices in one launch ----
__global__ __launch_bounds__(256) void f2bf_all(
    const float* __restrict__ w0, const float* __restrict__ w1,
    const float* __restrict__ w2, const float* __restrict__ w3,
    short* __restrict__ o0, short* __restrict__ o1,
    short* __restrict__ o2, short* __restrict__ o3){
  int idx = blockIdx.x*256 + threadIdx.x;
  int m = idx >> 15, r = idx & 32767;
  const float* src = (m==0) ? w0 : (m==1) ? w1 : (m==2) ? w2 : w3;
  short* dst       = (m==0) ? o0 : (m==1) ? o1 : (m==2) ? o2 : o3;
  const float4* p = (const float4*)src + (long long)r*2;
  float4 a = p[0], c = p[1];
  bf16x8 v;
  v[0]=f2bf(a.x); v[1]=f2bf(a.y); v[2]=f2bf(a.z); v[3]=f2bf(a.w);
  v[4]=f2bf(c.x); v[5]=f2bf(c.y); v[6]=f2bf(c.z); v[7]=f2bf(c.w);
  *(bf16x8*)&dst[(long long)r*8] = v;
}

// ---------------- row softmax in place over bf16 rows of length 4096 -----------
__global__ __launch_bounds__(256) void softmax_rows(short* __restrict__ S){
  long long row = blockIdx.x;
  short* p = S + row*4096;
  int t = threadIdx.x;
  bf16x8 v0 = *(bf16x8*)&p[t*16];
  bf16x8 v1 = *(bf16x8*)&p[t*16 + 8];
  float f[16];
  #pragma unroll
  for (int e = 0; e < 8; e++){ f[e] = bf2f(v0[e]); f[8+e] = bf2f(v1[e]); }
  float m = f[0];
  #pragma unroll
  for (int e = 1; e < 16; e++) m = fmaxf(m, f[e]);
  #pragma unroll
  for (int o = 32; o; o >>= 1) m = fmaxf(m, __shfl_xor(m, o));
  __shared__ float red[4];
  int wid = t >> 6;
  if ((t & 63) == 0) red[wid] = m;
  __syncthreads();
  m = fmaxf(fmaxf(red[0], red[1]), fmaxf(red[2], red[3]));
  float s = 0.f;
  #pragma unroll
  for (int e = 0; e < 16; e++){ f[e] = exp2f((f[e]-m)*1.4426950408889634f); s += f[e]; }
  #pragma unroll
  for (int o = 32; o; o >>= 1) s += __shfl_xor(s, o);
  __syncthreads();
  if ((t & 63) == 0) red[wid] = s;
  __syncthreads();
  s = red[0]+red[1]+red[2]+red[3];
  float inv = 1.f/s;
  #pragma unroll
  for (int e = 0; e < 8; e++){ v0[e] = f2bf(f[e]*inv); v1[e] = f2bf(f[8+e]*inv); }
  *(bf16x8*)&p[t*16]     = v0;
  *(bf16x8*)&p[t*16 + 8] = v1;
}

// ======== pipelined 256xBN bf16 GEMM: counted-lgkm DS/MFMA overlap ===========
// C = (A . B^T + bias) * scale. A [M][Kd], B [Nn][Kd] bf16 row-major.
// 512 thr / 8 waves, BK=64, double-buffered LDS, 2 barriers per K-tile.
// Reads issue in fenced groups; MFMA quadrants wait counted lgkmcnt so the DS
// pipe services later groups during earlier quadrants' MFMA.
// T2 XOR swizzle (pre-swizzled global source, linear gload dest, swizzled read).
// SWZ: XCD-region block swizzle (4x4 (M,N)-tile regions per XCD).
// MODE 0: bf16 [M][Nn] (swapped-operand MFMA, direct bf16x4 stores)
// MODE 1: bf16 transposed [Nn][M]
// MODE 2: fp32 transposed [Nn][M] + residual
template<int MODE, int BN, bool SWZ>
__global__ __launch_bounds__(512, 2) void gemmP(
    const short* __restrict__ A, const short* __restrict__ Bw,
    const float* __restrict__ bias,
    void* __restrict__ outp, const float* __restrict__ resid,
    int M, int Nn, int Kd,
    long long sA, long long sB, long long sO, float scale)
{
  constexpr int WN = 64;
  constexpr int WARPS_N = BN/WN;         // 4 (BN=256) or 2 (BN=128)
  constexpr int WARPS_M = 8/WARPS_N;     // 2 or 4
  constexpr int WM = 256/WARPS_M;        // 128 or 64
  constexpr int MF = WM/16;              // 8 or 4
  constexpr int MF2 = MF/2;              // 4 or 2
  constexpr int ABUF = 32768;            // A tile 256x64 bf16
  constexpr int BBUF = BN*128;
  constexpr int BUFSZ = ABUF + BBUF;
  constexpr int BLOADS = BN/64;          // gloads per thread for B
  constexpr int LOADS = 4 + BLOADS;      // total gloads per thread per K-tile
  extern __shared__ char smem[];

  int bx, by, bz;
  if constexpr (SWZ){
    // XCD c = id%8 gets 4x4 (bx,by) regions; 2 regions live per XCD ~= L2
    int id = blockIdx.x;
    int c = id & 7, s = id >> 3;
    int region = c + ((s >> 4) << 3);
    int o = s & 15;
    bz = region >> 4;
    bx = (region & 3)*4 + (o & 3);
    by = ((region >> 2) & 3)*4 + (o >> 2);
  } else { bx = blockIdx.x; by = blockIdx.y; bz = blockIdx.z; }

  const short* Ab = A + bz*sA;
  const short* Bb = Bw + bz*sB;
  const int m0 = bx*256, n0 = by*BN;
  const int t = threadIdx.x;
  const int lane = t & 63, wid = t >> 6;
  const int g = lane >> 4, lr = lane & 15;
  const int wr = wid / WARPS_N, wc = wid % WARPS_N;
  const long long KdLL = Kd;

  // staging: thread t stages 16B chunk ((t&7)^(row&7)) of row (t>>3) (+j*64)
  const int r0 = t >> 3;
  const int c0s = ((t & 7) ^ (r0 & 7)) * 8;
  const short* pA0 = Ab + (long long)(m0 + r0)*KdLL + c0s;
  const short* pB0 = Bb + (long long)(n0 + r0)*KdLL + c0s;

  // LDS layouts: A [256][64] bf16 at 0, B [BN][64] at ABUF; row r swizzled ^(r&7)
  int roA[MF], swA[MF], roB[4], swB[4];
  #pragma unroll
  for (int mf = 0; mf < MF; mf++){
    int ra = wr*WM + mf*16 + lr;
    roA[mf] = ra*128; swA[mf] = ra & 7;
  }
  #pragma unroll
  for (int nf = 0; nf < 4; nf++){
    int cb = wc*WN + nf*16 + lr;
    roB[nf] = ABUF + cb*128; swB[nf] = cb & 7;
  }

  f32x4 acc[MF][4];
  #pragma unroll
  for (int i = 0; i < MF; i++)
    #pragma unroll
    for (int j = 0; j < 4; j++)
      acc[i][j] = f32x4{0.f,0.f,0.f,0.f};
  bf16x8 av[MF2][2], bv[4][2];   // av reused for low/high half of A frags

  auto STAGE = [&](int kt, int buf){
    char* d = smem + buf*BUFSZ;
    const short* sa = pA0 + (long long)kt*64;
    #pragma unroll
    for (int j = 0; j < 4; j++)
      gload_lds16(sa + (long long)j*64*KdLL, d + j*8192 + t*16);
    const short* sb = pB0 + (long long)kt*64;
    #pragma unroll
    for (int j = 0; j < BLOADS; j++)
      gload_lds16(sb + (long long)j*64*KdLL, d + ABUF + j*8192 + t*16);
  };

  #define RD_AV(HI)                                                          \
    _Pragma("unroll")                                                        \
    for (int i = 0; i < MF2; i++){                                           \
      _Pragma("unroll")                                                      \
      for (int ks = 0; ks < 2; ks++)                                         \
        av[i][ks] = *(const bf16x8*)(base + roA[(HI)*MF2+i] +                \
                      ((((ks<<2)+g) ^ swA[(HI)*MF2+i])<<4));                 \
    }
  #define RD_BV(J0)                                                          \
    _Pragma("unroll")                                                        \
    for (int j = 0; j < 2; j++){                                             \
      _Pragma("unroll")                                                      \
      for (int ks = 0; ks < 2; ks++)                                         \
        bv[(J0)+j][ks] = *(const bf16x8*)(base + roB[(J0)+j] +               \
                      ((((ks<<2)+g) ^ swB[(J0)+j])<<4));                     \
    }
  #define QUAD(QM, QN)                                                       \
    __builtin_amdgcn_s_setprio(1);                                           \
    _Pragma("unroll")                                                        \
    for (int i = 0; i < MF2; i++)                                            \
      _Pragma("unroll")                                                      \
      for (int j = 0; j < 2; j++)                                            \
        _Pragma("unroll")                                                    \
        for (int ks = 0; ks < 2; ks++){                                      \
          if constexpr (MODE == 0)                                           \
            acc[(QM)*MF2+i][(QN)*2+j] = __builtin_amdgcn_mfma_f32_16x16x32_bf16( \
              bv[(QN)*2+j][ks], av[i][ks], acc[(QM)*MF2+i][(QN)*2+j], 0,0,0);\
          else                                                               \
            acc[(QM)*MF2+i][(QN)*2+j] = __builtin_amdgcn_mfma_f32_16x16x32_bf16( \
              av[i][ks], bv[(QN)*2+j][ks], acc[(QM)*MF2+i][(QN)*2+j], 0,0,0);\
        }                                                                    \
    __builtin_amdgcn_s_setprio(0);

  const int NT = Kd >> 6;

  STAGE(0, 0);
  STAGE(1, 1);
  if constexpr (LOADS == 8) asm volatile("s_waitcnt vmcnt(8)" ::: "memory");
  else                      asm volatile("s_waitcnt vmcnt(6)" ::: "memory");
  SB0();
  __builtin_amdgcn_s_barrier();

  for (int it = 0; it < NT; ++it){
    char* base = smem + (it & 1)*BUFSZ;
    const bool more = (it + 2 < NT);
    // group 1: A-low frags + B-low frags (12 or 8 reads)
    RD_AV(0); RD_BV(0); SB0();
    // group 2: B-high frags (4 reads)
    RD_BV(2); SB0();
    LGKM4();            // group 1 complete (<=4 outstanding)
    QUAD(0,0);
    LGKM0();            // group 2 complete
    QUAD(0,1);
    SB0();
    // group 3: A-high frags into reused av regs (av-old dead after QUAD(0,1))
    RD_AV(1); SB0();
    LGKM0();
    QUAD(1,0);
    SB0();
    __builtin_amdgcn_s_barrier();       // all waves done reading buf[cur]
    if (more) STAGE(it + 2, it & 1);    // overwrite buf[cur]
    QUAD(1,1);
    SB0();
    if (more){
      if constexpr (LOADS == 8) asm volatile("s_waitcnt vmcnt(8)" ::: "memory");
      else                      asm volatile("s_waitcnt vmcnt(6)" ::: "memory");
    } else {
      asm volatile("s_waitcnt vmcnt(0)" ::: "memory");
    }
    SB0();
    __builtin_amdgcn_s_barrier();       // buf[nxt] staged for all waves
  }

  if constexpr (MODE == 0){
    // swapped operands: lane dim = rows, reg dim = 4 consecutive cols
    short* outb = (short*)outp + bz*sO;
    const bool hb = (bias != nullptr);
    #pragma unroll
    for (int mi = 0; mi < MF; mi++){
      int row = m0 + wr*WM + mi*16 + lr;
      #pragma unroll
      for (int ni = 0; ni < 4; ni++){
        int col = n0 + wc*WN + ni*16 + g*4;
        float b0=0.f,b1=0.f,b2=0.f,b3=0.f;
        if (hb){ float4 bb = *(const float4*)&bias[col]; b0=bb.x; b1=bb.y; b2=bb.z; b3=bb.w; }
        bf16x4 pk;
        pk[0] = f2bf((acc[mi][ni][0] + b0)*scale);
        pk[1] = f2bf((acc[mi][ni][1] + b1)*scale);
        pk[2] = f2bf((acc[mi][ni][2] + b2)*scale);
        pk[3] = f2bf((acc[mi][ni][3] + b3)*scale);
        *(bf16x4*)&outb[(long long)row*Nn + col] = pk;
      }
    }
  } else if constexpr (MODE == 1){
    short* outb = (short*)outp + bz*sO;
    #pragma unroll
    for (int ni = 0; ni < 4; ni++){
      int col = n0 + wc*WN + ni*16 + lr;
      float bv2 = bias ? bias[col] : 0.f;
      #pragma unroll
      for (int mi = 0; mi < MF; mi++){
        int row = m0 + wr*WM + mi*16 + g*4;
        bf16x4 pk;
        #pragma unroll
        for (int i = 0; i < 4; i++) pk[i] = f2bf((acc[mi][ni][i] + bv2)*scale);
        *(bf16x4*)&outb[(long long)col*M + row] = pk;
      }
    }
  } else {
    float* outb = (float*)outp + bz*sO;
    const float* rx = resid + bz*sO;
    #pragma unroll
    for (int ni = 0; ni < 4; ni++){
      int col = n0 + wc*WN + ni*16 + lr;
      float bv2 = bias[col];
      #pragma unroll
      for (int mi = 0; mi < MF; mi++){
        int row = m0 + wr*WM + mi*16 + g*4;
        long long off = (long long)col*M + row;
        float4 xr = *(const float4*)&rx[off];
        float4 o;
        o.x = acc[mi][ni][0] + bv2 + xr.x;
        o.y = acc[mi][ni][1] + bv2 + xr.y;
        o.z = acc[mi][ni][2] + bv2 + xr.z;
        o.w = acc[mi][ni][3] + bv2 + xr.w;
        *(float4*)&outb[off] = o;
      }
    }
  }
  #undef RD_AV
  #undef RD_BV
  #undef QUAD
}

extern "C" void kernel_launch(void* const* d_in, const int* in_sizes, int n_in,
                              void* d_out, int out_size, void* d_ws, size_t ws_size,
                              hipStream_t stream)
{
  const float* x   = (const float*)d_in[0];
  const float* gnw = (const float*)d_in[1];
  const float* gnb = (const float*)d_in[2];
  const float* Wq  = (const float*)d_in[3];
  const float* bq  = (const float*)d_in[4];
  const float* Wk  = (const float*)d_in[5];
  const float* bk  = (const float*)d_in[6];
  const float* Wv  = (const float*)d_in[7];
  const float* bvp = (const float*)d_in[8];
  const float* Wo  = (const float*)d_in[9];
  const float* bo  = (const float*)d_in[10];
  float* out = (float*)d_out;

  char* ws = (char*)d_ws;
  const size_t MB = 1ull << 20;
  short* h    = (short*)(ws);
  short* q    = (short*)(ws + 16*MB);
  short* kmat = (short*)(ws + 32*MB);
  short* vt   = (short*)(ws + 48*MB);
  short* ao   = (short*)(ws + 64*MB);
  short* wqb  = (short*)(ws + 80*MB);
  short* wkb  = wqb + 262144;
  short* wvb  = wkb + 262144;
  short* wob  = wvb + 262144;
  float* stats= (float*)(ws + 82*MB);
  short* S    = (short*)(ws + 84*MB);   // 128 MB (full path)

  const int LDS256 = 131072, LDS128 = 98304;
  hipFuncSetAttribute(reinterpret_cast<const void*>(&gemmP<0,256,true>),
                      hipFuncAttributeMaxDynamicSharedMemorySize, LDS256);
  hipFuncSetAttribute(reinterpret_cast<const void*>(&gemmP<0,128,false>),
                      hipFuncAttributeMaxDynamicSharedMemorySize, LDS128);
  hipFuncSetAttribute(reinterpret_cast<const void*>(&gemmP<1,128,false>),
                      hipFuncAttributeMaxDynamicSharedMemorySize, LDS128);
  hipFuncSetAttribute(reinterpret_cast<const void*>(&gemmP<2,128,false>),
                      hipFuncAttributeMaxDynamicSharedMemorySize, LDS128);

  dim3 blk(256);
  dim3 blk512(512);
  gn_stats<<<dim3(128), blk, 0, stream>>>(x, stats);
  gn_apply<<<dim3(64,4), blk, 0, stream>>>(x, stats, gnw, gnb, h);
  f2bf_all<<<dim3(512), blk, 0, stream>>>(Wq, Wk, Wv, Wo, wqb, wkb, wvb, wob);

  const long long sTok = 4096ll*512;
  const long long sS   = 4096ll*4096;
  const float qscale = 0.044194173824159216f;  // 1/sqrt(512)

  // Q (scale folded), K, V(transposed out)
  gemmP<0,128,false><<<dim3(16,4,4), blk512, LDS128, stream>>>(h, wqb, bq,  q,    nullptr, 4096, 512, 512, sTok, 0, sTok, qscale);
  gemmP<0,128,false><<<dim3(16,4,4), blk512, LDS128, stream>>>(h, wkb, bk,  kmat, nullptr, 4096, 512, 512, sTok, 0, sTok, 1.f);
  gemmP<1,128,false><<<dim3(16,4,4), blk512, LDS128, stream>>>(h, wvb, bvp, vt,   nullptr, 4096, 512, 512, sTok, 0, sTok, 1.f);

  if (ws_size >= 212*MB){
    gemmP<0,256,true><<<dim3(1024), blk512, LDS256, stream>>>(q, kmat, nullptr, S, nullptr, 4096, 4096, 512, sTok, sTok, sS, 1.f);
    softmax_rows<<<dim3(16384), blk, 0, stream>>>(S);
    gemmP<0,128,false><<<dim3(16,4,4), blk512, LDS128, stream>>>(S, vt, nullptr, ao, nullptr, 4096, 512, 4096, sS, sTok, sTok, 1.f);
  } else {
    for (int b = 0; b < 4; b++){
      gemmP<0,256,true><<<dim3(256), blk512, LDS256, stream>>>(q + b*sTok, kmat + b*sTok, nullptr, S, nullptr, 4096, 4096, 512, 0, 0, 0, 1.f);
      softmax_rows<<<dim3(4096), blk, 0, stream>>>(S);
      gemmP<0,128,false><<<dim3(16,4,1), blk512, LDS128, stream>>>(S, vt + b*sTok, nullptr, ao + b*sTok, nullptr, 4096, 512, 4096, 0, 0, 0, 1.f);
    }
  }

  // O-projection + bias + residual + transpose to [B, C, N] fp32
  gemmP<2,128,false><<<dim3(16,4,4), blk512, LDS128, stream>>>(ao, wob, bo, out, x, 4096, 512, 512, sTok, 0, sTok, 1.f);
}